// Round 3
// baseline (369.650 us; speedup 1.0000x reference)
//
#include <hip/hip_runtime.h>
#include <cstdint>
#include <cstddef>

#define T_SEQ 2048
#define D_MODEL 2048
#define NH 32
#define NKVH 8
#define HDIM 64

typedef _Float16 f16;
typedef __attribute__((ext_vector_type(8))) _Float16 half8;
typedef __attribute__((ext_vector_type(4))) _Float16 half4;
typedef __attribute__((ext_vector_type(4))) float floatx4;

__device__ __forceinline__ void gload_lds16(const void* g, void* l) {
  __builtin_amdgcn_global_load_lds(
      (const __attribute__((address_space(1))) void*)g,
      (__attribute__((address_space(3))) void*)l,
      16, 0, 0);
}

// ---------------- cast x (fp32 -> fp16), 4 elems/thread ----------------
__global__ __launch_bounds__(256) void cvt_f16_kernel(const float* __restrict__ in,
                                                      f16* __restrict__ out, int n4) {
  int id = blockIdx.x * 256 + threadIdx.x;
  if (id >= n4) return;
  float4 v = ((const float4*)in)[id];
  half4 o;
  o[0] = (f16)v.x; o[1] = (f16)v.y; o[2] = (f16)v.z; o[3] = (f16)v.w;
  ((half4*)out)[id] = o;
}

// ------------- transpose + cast: in [K][N] f32 -> out [N][K] f16 -------------
// grid (N/64, K/64), block 256
__global__ __launch_bounds__(256) void transpose_cvt_kernel(const float* __restrict__ in,
                                                            f16* __restrict__ out,
                                                            int N, int K) {
  __shared__ f16 tile[64 * 65];
  int tid = threadIdx.x;
  int n0 = blockIdx.x * 64, k0 = blockIdx.y * 64;
#pragma unroll
  for (int i = 0; i < 16; i++) {
    int idx = i * 256 + tid;
    int kk = idx >> 6, nn = idx & 63;
    tile[nn * 65 + kk] = (f16)in[(size_t)(k0 + kk) * N + n0 + nn];
  }
  __syncthreads();
#pragma unroll
  for (int i = 0; i < 16; i++) {
    int idx = i * 256 + tid;
    int nn = idx >> 6, kk = idx & 63;
    out[(size_t)(n0 + nn) * K + k0 + kk] = tile[nn * 65 + kk];
  }
}

// ---------------- GEMM: C[M][N] = A[M][K] * B[K][N], BT is [N][K] ----------------
// 128x128 tile, BK=64, 4 waves (2x2), 16x16x32 f16 MFMA. global_load_lds width16.
// OutT = float or f16.
template <typename OutT>
__global__ __launch_bounds__(256) void gemm_f16_kernel(const f16* __restrict__ A,
                                                       const f16* __restrict__ BT,
                                                       OutT* __restrict__ C,
                                                       int M, int N, int K) {
  __shared__ alignas(16) f16 As[128 * 64];
  __shared__ alignas(16) f16 Bs[128 * 64];
  int tid = threadIdx.x;
  int wave = tid >> 6, lane = tid & 63;
  int ln15 = lane & 15, quad = lane >> 4;
  int wr = wave >> 1, wc = wave & 1;
  int bm = blockIdx.y, bn = blockIdx.x;
  const f16* Ab = A + (size_t)bm * 128 * K;
  const f16* Bb = BT + (size_t)bn * 128 * K;
  int srow = wave * 32 + (lane >> 3);   // row within 128-row tile this lane stages
  int scol = (lane & 7) * 8;            // k-offset within 64-wide k-slab
  floatx4 acc[4][4];
  floatx4 zero = {0.f, 0.f, 0.f, 0.f};
#pragma unroll
  for (int mt = 0; mt < 4; mt++)
#pragma unroll
    for (int nt = 0; nt < 4; nt++) acc[mt][nt] = zero;

  for (int k0 = 0; k0 < K; k0 += 64) {
#pragma unroll
    for (int i = 0; i < 4; i++) {
      // LDS dest is wave-uniform; lane's 16B lands at base + lane*16 = row-major [128][64]
      gload_lds16(Ab + (size_t)(srow + i * 8) * K + k0 + scol, &As[(wave * 32 + i * 8) * 64]);
      gload_lds16(Bb + (size_t)(srow + i * 8) * K + k0 + scol, &Bs[(wave * 32 + i * 8) * 64]);
    }
    __syncthreads();
#pragma unroll
    for (int kk = 0; kk < 64; kk += 32) {
      half8 af[4], bf[4];
#pragma unroll
      for (int mt = 0; mt < 4; mt++)
        af[mt] = *(const half8*)&As[(wr * 64 + mt * 16 + ln15) * 64 + kk + quad * 8];
#pragma unroll
      for (int nt = 0; nt < 4; nt++)
        bf[nt] = *(const half8*)&Bs[(wc * 64 + nt * 16 + ln15) * 64 + kk + quad * 8];
#pragma unroll
      for (int mt = 0; mt < 4; mt++)
#pragma unroll
        for (int nt = 0; nt < 4; nt++)
          acc[mt][nt] = __builtin_amdgcn_mfma_f32_16x16x32_f16(af[mt], bf[nt], acc[mt][nt], 0, 0, 0);
    }
    __syncthreads();
  }
  size_t rbase = (size_t)bm * 128 + wr * 64;
  int cbase = bn * 128 + wc * 64;
#pragma unroll
  for (int mt = 0; mt < 4; mt++)
#pragma unroll
    for (int nt = 0; nt < 4; nt++)
#pragma unroll
      for (int r = 0; r < 4; r++)
        C[(rbase + mt * 16 + quad * 4 + r) * (size_t)N + cbase + nt * 16 + ln15] =
            (OutT)acc[mt][nt][r];
}

// ---------------- RoPE + split to per-head layout (fp16 in, fp16 out) ----------------
// qkv: [T][3072] f16. qr: [32][T][64], kr/vr: [8][T][64] f16. one thread = one col pair.
__global__ __launch_bounds__(256) void rope_split_kernel(const f16* __restrict__ qkv,
                                                         const float* __restrict__ freqs,
                                                         f16* __restrict__ qr,
                                                         f16* __restrict__ kr,
                                                         f16* __restrict__ vr) {
  int id = blockIdx.x * 256 + threadIdx.x;  // [0, T*1536)
  int t = id / 1536;
  int pr = id - t * 1536;
  int c0 = pr * 2;
  const f16* row = qkv + (size_t)t * 3072;
  if (c0 < 2048) {
    int h = c0 >> 6, p = (c0 & 63) >> 1;
    float ang = freqs[t * 32 + p];
    float s, c;
    __sincosf(ang, &s, &c);
    float t1 = (float)row[c0], t2 = (float)row[c0 + 1];
    f16* dst = qr + ((size_t)h * T_SEQ + t) * 64 + (c0 & 63);
    dst[0] = (f16)(t1 * c - t2 * s);
    dst[1] = (f16)(t1 * s + t2 * c);
  } else if (c0 < 2560) {
    int cc = c0 - 2048;
    int kh = cc >> 6, p = (cc & 63) >> 1;
    float ang = freqs[t * 32 + p];
    float s, c;
    __sincosf(ang, &s, &c);
    float t1 = (float)row[c0], t2 = (float)row[c0 + 1];
    f16* dst = kr + ((size_t)kh * T_SEQ + t) * 64 + (cc & 63);
    dst[0] = (f16)(t1 * c - t2 * s);
    dst[1] = (f16)(t1 * s + t2 * c);
  } else {
    int cc = c0 - 2560;
    int kh = cc >> 6;
    f16* dst = vr + ((size_t)kh * T_SEQ + t) * 64 + (cc & 63);
    dst[0] = row[c0];
    dst[1] = row[c0 + 1];
  }
}

// ---------------- flash attention, causal, GQA ----------------
// grid (T/64, H), block 256 (4 waves); wave w owns q rows qbase+16w..+15.
__global__ __launch_bounds__(256) void attn_fwd_kernel(const f16* __restrict__ q,
                                                       const f16* __restrict__ k,
                                                       const f16* __restrict__ v,
                                                       f16* __restrict__ o) {
  __shared__ alignas(16) f16 Ks[64 * 72];   // K-tile [key][d], padded
  __shared__ alignas(16) f16 Vt[64 * 72];   // V-tile transposed [d][key]
  __shared__ alignas(16) float Sf[64 * 65]; // score tile fp32
  __shared__ alignas(16) f16 Pb[64 * 72];   // probabilities fp16 (A-operand layout source)
  __shared__ alignas(16) float mS[64], lS[64], aS[64];

  int tid = threadIdx.x;
  int lane = tid & 63, w = tid >> 6;
  int ln15 = lane & 15, quad = lane >> 4;
  int qt = blockIdx.x, h = blockIdx.y;
  int kvh = h >> 2;  // G = 4
  int qbase = qt * 64;

  const f16* qh = q + ((size_t)h * T_SEQ + qbase) * 64;
  const f16* kh = k + (size_t)kvh * T_SEQ * 64;
  const f16* vh = v + (size_t)kvh * T_SEQ * 64;

  // Q fragments (A layout): lane holds row (w*16+ln15), cols quad*8.. (+32)
  half8 qf0 = *(const half8*)&qh[(size_t)(w * 16 + ln15) * 64 + quad * 8];
  half8 qf1 = *(const half8*)&qh[(size_t)(w * 16 + ln15) * 64 + 32 + quad * 8];

  floatx4 oacc[4];
  floatx4 zero = {0.f, 0.f, 0.f, 0.f};
#pragma unroll
  for (int nt = 0; nt < 4; nt++) oacc[nt] = zero;
  if (tid < 64) { mS[tid] = -1e30f; lS[tid] = 0.f; }

  for (int jt = 0; jt <= qt; jt++) {
    __syncthreads();  // protect Ks/Vt/(init) from previous iteration readers
    // stage K tile and transposed V tile
#pragma unroll
    for (int i = 0; i < 2; i++) {
      int idx = i * 256 + tid;
      int row = idx >> 3, c8 = idx & 7;
      half8 k8 = *(const half8*)&kh[(size_t)(jt * 64 + row) * 64 + c8 * 8];
      *(half8*)&Ks[row * 72 + c8 * 8] = k8;
      half8 v8 = *(const half8*)&vh[(size_t)(jt * 64 + row) * 64 + c8 * 8];
#pragma unroll
      for (int e = 0; e < 8; e++) Vt[(c8 * 8 + e) * 72 + row] = v8[e];
    }
    __syncthreads();

    // S = Q K^T  (16x64 per wave)
    floatx4 sacc[4];
#pragma unroll
    for (int nt = 0; nt < 4; nt++) {
      half8 b0 = *(const half8*)&Ks[(nt * 16 + ln15) * 72 + quad * 8];
      half8 b1 = *(const half8*)&Ks[(nt * 16 + ln15) * 72 + 32 + quad * 8];
      sacc[nt] = __builtin_amdgcn_mfma_f32_16x16x32_f16(qf0, b0, zero, 0, 0, 0);
      sacc[nt] = __builtin_amdgcn_mfma_f32_16x16x32_f16(qf1, b1, sacc[nt], 0, 0, 0);
    }
    bool diag = (jt == qt);
#pragma unroll
    for (int nt = 0; nt < 4; nt++)
#pragma unroll
      for (int r = 0; r < 4; r++) {
        int row_loc = w * 16 + quad * 4 + r;
        int col_loc = nt * 16 + ln15;
        float sv = sacc[nt][r] * 0.125f;  // 1/sqrt(64)
        if (diag && col_loc > row_loc) sv = -1e30f;
        Sf[row_loc * 65 + col_loc] = sv;
      }
    __syncthreads();

    // online softmax: 4 threads per row (16 cols each)
    {
      int r = tid >> 2, sg = tid & 3;
      const float* srow = &Sf[r * 65 + sg * 16];
      float vals[16];
      float mx = -1e30f;
#pragma unroll
      for (int c2 = 0; c2 < 16; c2++) { vals[c2] = srow[c2]; mx = fmaxf(mx, vals[c2]); }
      mx = fmaxf(mx, __shfl_xor(mx, 1));
      mx = fmaxf(mx, __shfl_xor(mx, 2));
      float mprev = mS[r];
      float mnew = fmaxf(mprev, mx);
      float sum = 0.f;
      f16* prow = &Pb[r * 72 + sg * 16];
#pragma unroll
      for (int c2 = 0; c2 < 16; c2++) {
        float p = __expf(vals[c2] - mnew);
        sum += p;
        prow[c2] = (f16)p;
      }
      sum += __shfl_xor(sum, 1);
      sum += __shfl_xor(sum, 2);
      if (sg == 0) {
        aS[r] = __expf(mprev - mnew);
        lS[r] = lS[r] * __expf(mprev - mnew) + sum;
        mS[r] = mnew;
      }
    }
    __syncthreads();

    // rescale accumulator, then O += P V
    floatx4 arow = *(const floatx4*)&aS[w * 16 + quad * 4];
#pragma unroll
    for (int nt = 0; nt < 4; nt++)
#pragma unroll
      for (int r = 0; r < 4; r++) oacc[nt][r] *= arow[r];
    half8 pa0 = *(const half8*)&Pb[(w * 16 + ln15) * 72 + quad * 8];
    half8 pa1 = *(const half8*)&Pb[(w * 16 + ln15) * 72 + 32 + quad * 8];
#pragma unroll
    for (int nt = 0; nt < 4; nt++) {
      half8 b0 = *(const half8*)&Vt[(nt * 16 + ln15) * 72 + quad * 8];
      half8 b1 = *(const half8*)&Vt[(nt * 16 + ln15) * 72 + 32 + quad * 8];
      oacc[nt] = __builtin_amdgcn_mfma_f32_16x16x32_f16(pa0, b0, oacc[nt], 0, 0, 0);
      oacc[nt] = __builtin_amdgcn_mfma_f32_16x16x32_f16(pa1, b1, oacc[nt], 0, 0, 0);
    }
  }

  // normalize and write out [T][H*HD] fp16
  floatx4 lrow = *(const floatx4*)&lS[w * 16 + quad * 4];
#pragma unroll
  for (int nt = 0; nt < 4; nt++)
#pragma unroll
    for (int r = 0; r < 4; r++) {
      float val = oacc[nt][r] / lrow[r];
      int t = qbase + w * 16 + quad * 4 + r;
      int col = h * 64 + nt * 16 + ln15;
      o[(size_t)t * (NH * HDIM) + col] = (f16)val;
    }
}

extern "C" void kernel_launch(void* const* d_in, const int* in_sizes, int n_in,
                              void* d_out, int out_size, void* d_ws, size_t ws_size,
                              hipStream_t stream) {
  (void)in_sizes; (void)n_in; (void)out_size;
  const float* x = (const float*)d_in[0];
  const float* freqs = (const float*)d_in[1];
  const float* wq = (const float*)d_in[2];
  const float* wk = (const float*)d_in[3];
  const float* wv = (const float*)d_in[4];
  const float* wo = (const float*)d_in[5];
  float* out = (float*)d_out;
  char* ws = (char*)d_ws;
  const size_t MB = 1024 * 1024;

  // Defensive: this plan needs 28 MB of workspace. If the harness gives less,
  // no-op cleanly (diagnosable absmax failure) instead of corrupting memory.
  if (ws_size < 28 * MB) return;

  // Workspace plan (peak 28 MB), time-multiplexed:
  //   phase A (proj):  xb f16 @ [0,8), wcatT [3072][2048] f16 @ [8,20)
  //   phase B (rope):  qr [32][T][64] @ [0,8), kr @ [8,10), vr @ [10,12)  (xb/wcatT dead)
  //   phase C:         woT [2048][2048] f16 @ [12,20)
  //   phase D (attn):  ao [T][2048] f16 @ [20,28)
  // d_out (16 MB f32) doubles as scratch for qkvh [T][3072] f16 (12 MB);
  // gemm2 fully overwrites d_out at the end.
  f16* xb = (f16*)(ws);
  f16* qr = (f16*)(ws);                // after gemm1, xb is dead
  f16* wcatT = (f16*)(ws + 8 * MB);
  f16* kr = (f16*)(ws + 8 * MB);       // after gemm1, wcatT is dead
  f16* vr = (f16*)(ws + 10 * MB);
  f16* woT = (f16*)(ws + 12 * MB);
  f16* ao = (f16*)(ws + 20 * MB);
  f16* qkvh = (f16*)d_out;             // scratch inside d_out; overwritten by gemm2

  // 1. cast x to fp16
  cvt_f16_kernel<<<(T_SEQ * D_MODEL / 4 + 255) / 256, 256, 0, stream>>>(x, xb, T_SEQ * D_MODEL / 4);
  // 2. transpose-cast wq|wk|wv into concatenated [3072][2048] BT
  transpose_cvt_kernel<<<dim3(32, 32), 256, 0, stream>>>(wq, wcatT, 2048, 2048);
  transpose_cvt_kernel<<<dim3(8, 32), 256, 0, stream>>>(wk, wcatT + (size_t)2048 * 2048, 512, 2048);
  transpose_cvt_kernel<<<dim3(8, 32), 256, 0, stream>>>(wv, wcatT + (size_t)2560 * 2048, 512, 2048);
  // 3. qkvh = x @ [wq|wk|wv]   (M=2048, N=3072, K=2048), fp16 out into d_out scratch
  gemm_f16_kernel<f16><<<dim3(3072 / 128, 2048 / 128), 256, 0, stream>>>(xb, wcatT, qkvh,
                                                                         2048, 3072, 2048);
  // 4. RoPE + split to per-head fp16 (overlays xb/wcatT, both dead)
  rope_split_kernel<<<(T_SEQ * 1536) / 256, 256, 0, stream>>>(qkvh, freqs, qr, kr, vr);
  // 5. transpose-cast wo into ws[12,20)
  transpose_cvt_kernel<<<dim3(32, 32), 256, 0, stream>>>(wo, woT, 2048, 2048);
  // 6. causal GQA flash attention -> ao
  attn_fwd_kernel<<<dim3(T_SEQ / 64, NH), 256, 0, stream>>>(qr, kr, vr, ao);
  // 7. out = ao @ wo  (M=2048, N=2048, K=2048), fp32 out — overwrites qkvh scratch
  gemm_f16_kernel<float><<<dim3(2048 / 128, 2048 / 128), 256, 0, stream>>>(ao, woT, out,
                                                                           2048, 2048, 2048);
}